// Round 11
// baseline (4217.012 us; speedup 1.0000x reference)
//
#include <hip/hip_runtime.h>
#include <hip/hip_bf16.h>

#define EPSV 1e-12
#define RHASH 0.2

__device__ __forceinline__ int fmod2(double t) {
    // floor then mod 2 with numpy semantics (non-negative result)
    return (int)(((long long)floor(t)) & 1LL);
}

__device__ __forceinline__ void load_row6(const float* base, float* r) {
    float2 a0 = *(const float2*)(base);
    float2 a1 = *(const float2*)(base + 2);
    float2 a2 = *(const float2*)(base + 4);
    r[0] = a0.x; r[1] = a0.y; r[2] = a1.x; r[3] = a1.y; r[4] = a2.x; r[5] = a2.y;
}

__device__ __forceinline__ void load_row12(const float* base, float* r) {
    #pragma unroll
    for (int j = 0; j < 6; ++j) *(float2*)&r[2 * j] = *(const float2*)(base + 2 * j);
}

// 4 FMAs into acc[c][0..3] from rows cur/nxt
#define FMA4(c,kx,w) { float wg=(w); \
  acc[c][0]=fmaf(wg,cur[kx],acc[c][0]); acc[c][1]=fmaf(wg,cur[(kx)+1],acc[c][1]); \
  acc[c][2]=fmaf(wg,nxt[kx],acc[c][2]); acc[c][3]=fmaf(wg,nxt[(kx)+1],acc[c][3]); }

// ---------------------------------------------------------------------------
// layer_setup v2 (r9): wave-parallel reductions.
// dmeta layout: [0..2]=asum1, [3..18]=asum2, [19..38]=asum3, [39]=qc1,[40]=qc2,[41]=qc3
// imeta layout: [0..15]=kh1, [16..35]=kh2, [36..55]=kh3
// ---------------------------------------------------------------------------
__device__ void layer_setup(const float* W, const float* a, double cval,
                            int Co, int Ci, int* kh, double* asum, double* qc,
                            double* s_norm, float* Wbuf, float* abuf)
{
    const int t = threadIdx.x;
    const int w = t >> 6, ln = t & 63;
    const int D = Ci * 25;
    for (int i = t; i < Co * D; i += 256) Wbuf[i] = W[i];
    for (int i = t; i < D + 5; i += 256) abuf[i] = a[i];
    __syncthreads();
    // norms: wave-per-channel
    for (int co = w; co < Co; co += 4) {
        double s = 0;
        for (int j = ln; j < D; j += 64) { double x = (double)Wbuf[co * D + j]; s += x * x; }
        #pragma unroll
        for (int off = 32; off; off >>= 1) s += __shfl_xor(s, off);
        if (ln == 0) s_norm[co] = sqrt(s);
    }
    __syncthreads();
    if (t == 0) {
        double mx = 0;
        for (int i = 0; i < Co; ++i) mx = fmax(mx, s_norm[i]);
        s_norm[23] = 1.0 / (mx + EPSV);     // scratch slot: Co <= 20 < 23
    }
    __syncthreads();
    double scale = s_norm[23];
    // hash dot-products: wave-per-channel
    for (int co = w; co < Co; co += 4) {
        double dp = 0;
        for (int j = ln; j < D; j += 64) dp += (double)Wbuf[co * D + j] * (double)abuf[j];
        #pragma unroll
        for (int off = 32; off; off >>= 1) dp += __shfl_xor(dp, off);
        if (ln == 0) {
            dp *= scale;
            double n = s_norm[co] * scale;
            double p = n * n;               // n^2, n^4, n^8, n^16, n^32
            for (int m = 0; m < 5; ++m) { dp += p * (double)abuf[D + m]; p *= p; }
            kh[co] = fmod2((dp + cval) / RHASH);
        }
    }
    if (t >= 64 && t < 64 + Ci) {
        int c = t - 64;
        double s = 0;
        for (int j = 0; j < 25; ++j) s += (double)abuf[c * 25 + j];
        asum[c] = s;
    }
    if (t == 128) {
        double s = 0;
        for (int m = 0; m < 5; ++m) s += (double)abuf[D + m];
        *qc = 0.5 * s + cval;
    }
    __syncthreads();
}

// ---------------------------------------------------------------------------
// prep_kernel: fused setup + pack (r4). Blocks 0..2 = one hash layer each;
// blocks 3..86 = weight repack.
// Wp1: [ci3][ky5][kx5][co16] = 1200; Wp2: [ci16][ky5][cog4][28] = 8960;
// Wp3: [ci20][ky5][cog4][28] = 11200.
// ---------------------------------------------------------------------------
__global__ __launch_bounds__(256) void prep_kernel(
    const float* W1, const float* a1, const float* c1,
    const float* W2, const float* a2, const float* c2,
    const float* W3, const float* a3, const float* c3,
    double* dmeta, int* imeta,
    float* Wp1, float* Wp2, float* Wp3)
{
    __shared__ float Wbuf[10000];
    __shared__ float abuf[512];
    __shared__ double s_norm[24];
    const int blk = blockIdx.x;
    if (blk == 0) {
        layer_setup(W1, a1, (double)c1[0], 16, 3,  imeta + 0,  dmeta + 0,  dmeta + 39, s_norm, Wbuf, abuf);
    } else if (blk == 1) {
        layer_setup(W2, a2, (double)c2[0], 20, 16, imeta + 16, dmeta + 3,  dmeta + 40, s_norm, Wbuf, abuf);
    } else if (blk == 2) {
        layer_setup(W3, a3, (double)c3[0], 20, 20, imeta + 36, dmeta + 19, dmeta + 41, s_norm, Wbuf, abuf);
    } else {
        int i = (blk - 3) * 256 + threadIdx.x;
        if (i < 1200) {
            int co = i & 15, r = i >> 4;           // r = (ci*5+ky)*5+kx
            int kx = r % 5, r2 = r / 5, ky = r2 % 5, ci = r2 / 5;
            Wp1[i] = W1[co * 75 + ci * 25 + ky * 5 + kx];
        } else if (i < 1200 + 8960) {
            int k = i - 1200;
            int j = k % 28, r = k / 28;            // r = (ci*5+ky)*4+cog
            int cog = r % 4, r2 = r / 4, ky = r2 % 5, ci = r2 / 5;
            Wp2[k] = (j < 25) ? W2[(cog * 5 + j / 5) * 400 + ci * 25 + ky * 5 + (j % 5)] : 0.f;
        } else if (i < 1200 + 8960 + 11200) {
            int k = i - 10160;
            int j = k % 28, r = k / 28;
            int cog = r % 4, r2 = r / 4, ky = r2 % 5, ci = r2 / 5;
            Wp3[k] = (j < 25) ? W3[(cog * 5 + j / 5) * 500 + ci * 25 + ky * 5 + (j % 5)] : 0.f;
        }
    }
}

// ---------------------------------------------------------------------------
// conv1 v5: x[B,3,32,32] -> h1[B,16,16,16]; PERSISTENT block = 4 samples
// processed sequentially (grid B/4 = 1024 = exactly 4 blocks/CU, whole grid
// resident). Per-sample fixed costs removed: Ws (4.8KB) + halo zeros staged
// ONCE; sample k+1's x issued into regs BEFORE sample k's compute (true
// cross-sample T14: ~9600 FMA-cycles of latency cover); commit after the
// epilogue barrier (xs dead there). Same 2 barriers/sample as v4; inner
// loop and epilogue bit-identical. thread = (cog4 x py16 x pxg4), 4co x
// 2x8 strip, rolling rows, x stride 38. Fused qh1 (staging) / qh2 (epi).
// ---------------------------------------------------------------------------
__global__ __launch_bounds__(256) void conv1_kernel(
    const float* __restrict__ x, const float* __restrict__ Wp1,
    const float* __restrict__ b1, const int* __restrict__ kh1,
    const double* __restrict__ dmeta, float* __restrict__ h1,
    int* __restrict__ qh2, int B)
{
    __shared__ float xs[3][36][38];
    __shared__ float Ws[1200];
    __shared__ double s_red[3][4];
    __shared__ double s_ch[16][4];

    const int t = threadIdx.x;
    const int w = t >> 6, ln = t & 63;
    const int b0 = blockIdx.x * 4;

    // one-time staging: weights + halo-only zeros (halo persists across samples)
    for (int i = t; i < 600; i += 256) ((float2*)Ws)[i] = ((const float2*)Wp1)[i];
    // halo: per ci, rows {0,1,34,35} full (4x38) + rows 2..33 cols
    // {0,1,34,35,36,37} (32x6) = 344 cells; x3 ci = 1032.
    for (int i = t; i < 1032; i += 256) {
        int ci = i / 344, r = i - ci * 344;
        int row, col;
        if (r < 152) { int rr = r / 38; col = r - rr * 38; row = (rr < 2) ? rr : rr + 32; }
        else { int q = r - 152; row = 2 + q / 6; int cq = q - (q / 6) * 6; col = (cq < 2) ? cq : cq + 32; }
        xs[ci][row][col] = 0.f;
    }

    // sample 0: load, commit interior, fused qh1 partials
    {
        const bool vb = (b0 < B);
        const float2* xb2 = (const float2*)(x + (size_t)b0 * 3072);
        float2 rxv[6];
        #pragma unroll
        for (int j = 0; j < 6; ++j) rxv[j] = vb ? xb2[t + 256 * j] : make_float2(0.f, 0.f);
        double psum[3] = {0, 0, 0};
        #pragma unroll
        for (int j = 0; j < 6; ++j) {
            int i = t + 256 * j, rem = i & 511, row = rem >> 4, col2 = rem & 15;
            *(float2*)&xs[j >> 1][row + 2][col2 * 2 + 2] = rxv[j];
            psum[j >> 1] += (double)rxv[j].x + (double)rxv[j].y;
        }
        #pragma unroll
        for (int c = 0; c < 3; ++c) {
            double s = psum[c];
            #pragma unroll
            for (int off = 32; off; off >>= 1) s += __shfl_xor(s, off);
            if (ln == 0) s_red[c][w] = s;
        }
    }
    __syncthreads();   // Ws, halo, xs, s_red all visible

    const int cog = ln >> 4;
    const int py = 4 * w + ((ln >> 2) & 3), pxg = ln & 3;
    const int y0 = 2 * py, x0 = 8 * pxg;

    for (int k = 0; k < 4; ++k) {
        const int b = b0 + k;
        const bool vb = (b < B);

        // qh1 for this sample from s_red
        double dp = 0, nn = 0;
        #pragma unroll
        for (int c = 0; c < 3; ++c) {
            double cm = (s_red[c][0] + s_red[c][1] + s_red[c][2] + s_red[c][3]) * (1.0 / 1024.0);
            dp += cm * dmeta[c]; nn += cm * cm;
        }
        const int qh = fmod2((dp / (5.0 * sqrt(nn) + EPSV) + dmeta[39]) / RHASH);

        // prefetch next sample's x (lands under this sample's ~9600 FMA cycles)
        float2 nxt[6];
        if (k < 3) {
            const bool vn = (b + 1 < B);
            const float2* xn = (const float2*)(x + (size_t)(b + 1) * 3072);
            #pragma unroll
            for (int j = 0; j < 6; ++j) nxt[j] = vn ? xn[t + 256 * j] : make_float2(0.f, 0.f);
        }

        float accA[4][8], accB[4][8];
        #pragma unroll
        for (int c = 0; c < 4; ++c) {
            float bb = b1[cog * 4 + c];
            #pragma unroll
            for (int kk = 0; kk < 8; ++kk) { accA[c][kk] = bb; accB[c][kk] = bb; }
        }

        #pragma unroll
        for (int ci = 0; ci < 3; ++ci) {
            float ra[12], rb[12];
            load_row12(&xs[ci][y0][x0],     ra);
            load_row12(&xs[ci][y0 + 1][x0], rb);
            #pragma unroll
            for (int ky = 0; ky < 5; ++ky) {
                const float4* wq = (const float4*)&Ws[((ci * 5 + ky) * 5) * 16 + cog * 4];
                #pragma unroll
                for (int kx = 0; kx < 5; ++kx) {
                    float4 wv = wq[kx * 4];          // 4 co of this cog, stride 16 floats
                    { float wg = wv.x;
                      #pragma unroll
                      for (int kk = 0; kk < 8; ++kk) { accA[0][kk] = fmaf(wg, ra[kk + kx], accA[0][kk]);
                                                       accB[0][kk] = fmaf(wg, rb[kk + kx], accB[0][kk]); } }
                    { float wg = wv.y;
                      #pragma unroll
                      for (int kk = 0; kk < 8; ++kk) { accA[1][kk] = fmaf(wg, ra[kk + kx], accA[1][kk]);
                                                       accB[1][kk] = fmaf(wg, rb[kk + kx], accB[1][kk]); } }
                    { float wg = wv.z;
                      #pragma unroll
                      for (int kk = 0; kk < 8; ++kk) { accA[2][kk] = fmaf(wg, ra[kk + kx], accA[2][kk]);
                                                       accB[2][kk] = fmaf(wg, rb[kk + kx], accB[2][kk]); } }
                    { float wg = wv.w;
                      #pragma unroll
                      for (int kk = 0; kk < 8; ++kk) { accA[3][kk] = fmaf(wg, ra[kk + kx], accA[3][kk]);
                                                       accB[3][kk] = fmaf(wg, rb[kk + kx], accB[3][kk]); } }
                }
                if (ky < 4) {
                    #pragma unroll
                    for (int j = 0; j < 12; ++j) ra[j] = rb[j];
                    load_row12(&xs[ci][y0 + ky + 2][x0], rb);
                }
            }
        }

        // epilogue: masked pooled store + per-channel sums for qh2
        float* hb = h1 + (size_t)b * 4096 + py * 16 + pxg * 4;
        double csum[4];
        #pragma unroll
        for (int c = 0; c < 4; ++c) {
            int co = cog * 4 + c;
            float mask = (kh1[co] == qh) ? 1.f : 0.f;
            float v0 = fmaxf(fmaxf(accA[c][0], accA[c][1]), fmaxf(accB[c][0], accB[c][1]));
            float v1 = fmaxf(fmaxf(accA[c][2], accA[c][3]), fmaxf(accB[c][2], accB[c][3]));
            float v2 = fmaxf(fmaxf(accA[c][4], accA[c][5]), fmaxf(accB[c][4], accB[c][5]));
            float v3 = fmaxf(fmaxf(accA[c][6], accA[c][7]), fmaxf(accB[c][6], accB[c][7]));
            v0 = fmaxf(v0, 0.f) * mask; v1 = fmaxf(v1, 0.f) * mask;
            v2 = fmaxf(v2, 0.f) * mask; v3 = fmaxf(v3, 0.f) * mask;
            if (vb) *(float4*)(hb + co * 256) = make_float4(v0, v1, v2, v3);
            csum[c] = (double)v0 + (double)v1 + (double)v2 + (double)v3;
        }
        #pragma unroll
        for (int c = 0; c < 4; ++c) {
            double s = csum[c];
            s += __shfl_xor(s, 8); s += __shfl_xor(s, 4);
            s += __shfl_xor(s, 2); s += __shfl_xor(s, 1);
            if ((ln & 15) == 0) s_ch[cog * 4 + c][w] = s;
        }
        __syncthreads();   // s_ch ready; xs reads complete (xs dead)
        if (t == 0 && vb) {
            double dp2 = 0, nn2 = 0;
            #pragma unroll
            for (int c = 0; c < 16; ++c) {
                double cm = (s_ch[c][0] + s_ch[c][1] + s_ch[c][2] + s_ch[c][3]) * (1.0 / 256.0);
                dp2 += cm * dmeta[3 + c]; nn2 += cm * cm;
            }
            qh2[b] = fmod2((dp2 / (5.0 * sqrt(nn2) + EPSV) + dmeta[40]) / RHASH);
        }

        // commit next sample (xs dead past the epilogue barrier; s_red reads done)
        if (k < 3) {
            double ps[3] = {0, 0, 0};
            #pragma unroll
            for (int j = 0; j < 6; ++j) {
                int i = t + 256 * j, rem = i & 511, row = rem >> 4, col2 = rem & 15;
                *(float2*)&xs[j >> 1][row + 2][col2 * 2 + 2] = nxt[j];
                ps[j >> 1] += (double)nxt[j].x + (double)nxt[j].y;
            }
            #pragma unroll
            for (int c = 0; c < 3; ++c) {
                double s = ps[c];
                #pragma unroll
                for (int off = 32; off; off >>= 1) s += __shfl_xor(s, off);
                if (ln == 0) s_red[c][w] = s;
            }
            __syncthreads();   // xs + s_red ready for next sample
        }
    }
}

// ---------------------------------------------------------------------------
// conv2 v4 (r5/r9/r10-proven): h1 -> h2; block = 4 samples (wave=sample).
// thread = (s4 x cog4 x py8 x pxg2); 5co x 2x8 strip. T14 async-stage on x.
// VGPR 128 / LDS 37.9KB -> 4 blocks/CU. FROZEN — measured best (185us).
// ---------------------------------------------------------------------------
#define C2_XLOAD(CH, RX) { \
    _Pragma("unroll") \
    for (int j = 0; j < 8; ++j) { \
        int i = t + 256 * j, si = i >> 9, rem = i & 511, cil = rem >> 7, rr = rem & 127; \
        RX[j] = (b0 + si < B) ? ((const float2*)h1)[(size_t)(b0 + si) * 2048 + ((CH) * 4 + cil) * 128 + rr] \
                              : make_float2(0.f, 0.f); \
    } }

#define C2_XCOMMIT(RX) { \
    _Pragma("unroll") \
    for (int j = 0; j < 8; ++j) { \
        int i = t + 256 * j, si = i >> 9, rem = i & 511, cil = rem >> 7, rr = rem & 127; \
        int p2 = rr * 2, row = p2 >> 4, col = p2 & 15; \
        *(float2*)&xs[si][cil][row + 2][col + 2] = RX[j]; \
    } }

__global__ __launch_bounds__(256) void conv2_kernel(
    const float* __restrict__ h1, const float* __restrict__ Wp2,
    const float* __restrict__ b2, const int* __restrict__ kh2,
    const int* __restrict__ qh2, const double* __restrict__ dmeta,
    float* __restrict__ h2, int* __restrict__ qh3, int B)
{
    __shared__ float xs[4][4][20][22];   // [sample][ci][row][col] stride-22
    __shared__ float Ws[2240];           // [ci4][ky5][cog4][28]
    __shared__ double s_ch[4][20];

    const int b0 = blockIdx.x * 4, t = threadIdx.x;
    const int s = t >> 6, l = t & 63;
    const int cog = l >> 4, pos = l & 15;
    const int py = pos >> 1, pxg = pos & 1;
    const int b = b0 + s;

    for (int i = t; i < 4 * 4 * 20 * 22; i += 256) (&xs[0][0][0][0])[i] = 0.f;

    const int qh = (b < B) ? qh2[b] : 0;
    float accA[5][8], accB[5][8];
    #pragma unroll
    for (int c = 0; c < 5; ++c) {
        float bb = b2[cog * 5 + c];
        #pragma unroll
        for (int k = 0; k < 8; ++k) { accA[c][k] = bb; accB[c][k] = bb; }
    }

    float2 rx[8];
    C2_XLOAD(0, rx);
    __syncthreads();   // zero-init visible before chunk-0 commit

    for (int ch = 0; ch < 4; ++ch) {
        for (int i = t; i < 1120; i += 256)
            ((float2*)Ws)[i] = ((const float2*)(Wp2 + ch * 2240))[i];
        C2_XCOMMIT(rx);
        __syncthreads();
        if (ch < 3) C2_XLOAD(ch + 1, rx);   // issued post-barrier: hides under compute

        for (int cil = 0; cil < 4; ++cil) {
            float ra[12], rb[12];
            load_row12(&xs[s][cil][2 * py][8 * pxg],     ra);
            load_row12(&xs[s][cil][2 * py + 1][8 * pxg], rb);
            #pragma unroll
            for (int ky = 0; ky < 5; ++ky) {
                float wv[28];
                const float4* wp = (const float4*)&Ws[((cil * 5 + ky) * 4 + cog) * 28];
                *(float4*)&wv[0]  = wp[0];
                *(float4*)&wv[4]  = wp[1];
                *(float4*)&wv[8]  = wp[2];
                *(float4*)&wv[12] = wp[3];
                *(float4*)&wv[16] = wp[4];
                *(float4*)&wv[20] = wp[5];
                *(float4*)&wv[24] = wp[6];
                #pragma unroll
                for (int c = 0; c < 5; ++c) {
                    #pragma unroll
                    for (int kx = 0; kx < 5; ++kx) {
                        float wg = wv[c * 5 + kx];
                        #pragma unroll
                        for (int k = 0; k < 8; ++k) {
                            accA[c][k] = fmaf(wg, ra[k + kx], accA[c][k]);
                            accB[c][k] = fmaf(wg, rb[k + kx], accB[c][k]);
                        }
                    }
                }
                if (ky < 4) {
                    #pragma unroll
                    for (int j = 0; j < 12; ++j) ra[j] = rb[j];
                    load_row12(&xs[s][cil][2 * py + ky + 2][8 * pxg], rb);
                }
            }
        }
        __syncthreads();
    }

    // masked pooled store (float4: 4 pooled px per co) + fused qh3
    float* ob = h2 + (size_t)b * 1280 + py * 8 + pxg * 4;
    double csum[5];
    #pragma unroll
    for (int c = 0; c < 5; ++c) {
        int co = cog * 5 + c;
        float mask = (kh2[co] == qh) ? 1.f : 0.f;
        float v0 = fmaxf(fmaxf(accA[c][0], accA[c][1]), fmaxf(accB[c][0], accB[c][1]));
        float v1 = fmaxf(fmaxf(accA[c][2], accA[c][3]), fmaxf(accB[c][2], accB[c][3]));
        float v2 = fmaxf(fmaxf(accA[c][4], accA[c][5]), fmaxf(accB[c][4], accB[c][5]));
        float v3 = fmaxf(fmaxf(accA[c][6], accA[c][7]), fmaxf(accB[c][6], accB[c][7]));
        v0 = fmaxf(v0, 0.f) * mask; v1 = fmaxf(v1, 0.f) * mask;
        v2 = fmaxf(v2, 0.f) * mask; v3 = fmaxf(v3, 0.f) * mask;
        if (b < B) *(float4*)(ob + co * 64) = make_float4(v0, v1, v2, v3);
        csum[c] = (double)v0 + (double)v1 + (double)v2 + (double)v3;
    }
    #pragma unroll
    for (int c = 0; c < 5; ++c) {
        double sv = csum[c];
        sv += __shfl_xor(sv, 8); sv += __shfl_xor(sv, 4);
        sv += __shfl_xor(sv, 2); sv += __shfl_xor(sv, 1);
        if (pos == 0) s_ch[s][cog * 5 + c] = sv;
    }
    __syncthreads();
    if (l == 0 && b < B) {
        double dp2 = 0, nn2 = 0;
        #pragma unroll
        for (int c = 0; c < 20; ++c) {
            double cm = s_ch[s][c] * (1.0 / 64.0);
            dp2 += cm * dmeta[19 + c]; nn2 += cm * cm;
        }
        qh3[b] = fmod2((dp2 / (5.0 * sqrt(nn2) + EPSV) + dmeta[41]) / RHASH);
    }
}

// ---------------------------------------------------------------------------
// conv3 + linear v2 (r5/r9-proven, reverted from r10's neutral v3):
// block = 4 samples, 256 threads; T14 async-stage split on Ws and x chunks.
// ---------------------------------------------------------------------------
#define C3_WLOAD(CH, RW) { \
    _Pragma("unroll") \
    for (int j = 0; j < 6; ++j) { \
        int i = t + 256 * j; \
        if (i < 1400) RW[j] = ((const float2*)(Wp3 + (CH) * 2800))[i]; \
    } }

#define C3_WCOMMIT(RW) { \
    _Pragma("unroll") \
    for (int j = 0; j < 6; ++j) { \
        int i = t + 256 * j; \
        if (i < 1400) ((float2*)Ws)[i] = RW[j]; \
    } }

#define C3_XLOAD(CH, RX) { \
    _Pragma("unroll") \
    for (int j = 0; j < 3; ++j) { \
        int i = t + 256 * j; \
        if (i < 640) { \
            int ss = i / 160, r = i - ss * 160, ci = r >> 5, rr = r & 31; \
            RX[j] = (b0 + ss < B) ? ((const float2*)(h2 + (size_t)(b0 + ss) * 1280 + ((CH) * 5 + ci) * 64))[rr] \
                                  : make_float2(0.f, 0.f); \
        } \
    } }

#define C3_XCOMMIT(RX) { \
    _Pragma("unroll") \
    for (int j = 0; j < 3; ++j) { \
        int i = t + 256 * j; \
        if (i < 640) { \
            int ss = i / 160, r = i - ss * 160, ci = r >> 5, rr = r & 31, p2 = rr * 2; \
            *(float2*)&xs[ss][ci][(p2 >> 3) + 2][(p2 & 7) + 2] = RX[j]; \
        } \
    } }

__global__ __launch_bounds__(256) void conv3_kernel(
    const float* __restrict__ h2, const float* __restrict__ Wp3,
    const float* __restrict__ b3, const int* __restrict__ kh3,
    const int* __restrict__ qh3,
    const float* __restrict__ Wo, const float* __restrict__ bo,
    float* __restrict__ out, int B)
{
    __shared__ float xs[4][5][12][12];
    __shared__ float Ws[2800];           // [ci5][ky5][cog4][28]
    __shared__ float flat[4][320];

    const int b0 = blockIdx.x * 4, t = threadIdx.x;
    const int s = t >> 6, q0 = t & 63, cog = q0 >> 4, pos = q0 & 15;
    const int py = pos >> 2, px = pos & 3;
    const int y0 = 2 * py, x0 = 2 * px;
    const int b = b0 + s;

    for (int i = t; i < 4 * 5 * 144; i += 256) (&xs[0][0][0][0])[i] = 0.f;

    const int qh = (b < B) ? qh3[b] : 0;
    float acc[5][4];
    #pragma unroll
    for (int c = 0; c < 5; ++c) {
        float bb = b3[cog * 5 + c];
        acc[c][0] = bb; acc[c][1] = bb; acc[c][2] = bb; acc[c][3] = bb;
    }

    float2 rw[6], rx[3];
    C3_WLOAD(0, rw);
    C3_XLOAD(0, rx);
    __syncthreads();   // zero-init visible before chunk-0 commit

    for (int ch = 0; ch < 4; ++ch) {
        C3_WCOMMIT(rw);
        C3_XCOMMIT(rx);
        __syncthreads();
        if (ch < 3) { C3_WLOAD(ch + 1, rw); C3_XLOAD(ch + 1, rx); }

        #pragma unroll
        for (int ci = 0; ci < 5; ++ci) {
            float cur[6], nxt[6];
            load_row6(&xs[s][ci][y0][x0], cur);
            load_row6(&xs[s][ci][y0 + 1][x0], nxt);
            #pragma unroll
            for (int ky = 0; ky < 5; ++ky) {
                const float* wrow = &Ws[((ci * 5 + ky) * 4 + cog) * 28];
                const float4* wq = (const float4*)wrow;
                float4 q;
                q = wq[0]; FMA4(0, 0, q.x) FMA4(0, 1, q.y) FMA4(0, 2, q.z) FMA4(0, 3, q.w)
                q = wq[1]; FMA4(0, 4, q.x) FMA4(1, 0, q.y) FMA4(1, 1, q.z) FMA4(1, 2, q.w)
                q = wq[2]; FMA4(1, 3, q.x) FMA4(1, 4, q.y) FMA4(2, 0, q.z) FMA4(2, 1, q.w)
                q = wq[3]; FMA4(2, 2, q.x) FMA4(2, 3, q.y) FMA4(2, 4, q.z) FMA4(3, 0, q.w)
                q = wq[4]; FMA4(3, 1, q.x) FMA4(3, 2, q.y) FMA4(3, 3, q.z) FMA4(3, 4, q.w)
                q = wq[5]; FMA4(4, 0, q.x) FMA4(4, 1, q.y) FMA4(4, 2, q.z) FMA4(4, 3, q.w)
                FMA4(4, 4, wrow[24])
                if (ky < 4) {
                    #pragma unroll
                    for (int j = 0; j < 6; ++j) cur[j] = nxt[j];
                    load_row6(&xs[s][ci][y0 + ky + 2][x0], nxt);
                }
            }
        }
        __syncthreads();
    }

    #pragma unroll
    for (int c = 0; c < 5; ++c) {
        int co = cog * 5 + c;
        float m = fmaxf(fmaxf(acc[c][0], acc[c][1]), fmaxf(acc[c][2], acc[c][3]));
        flat[s][co * 16 + pos] = fmaxf(m, 0.f) * ((kh3[co] == qh) ? 1.f : 0.f);
    }
    __syncthreads();

    // linear 320->10 for 4 samples: 40 (s,o) pairs x 4 lanes each
    if (t < 160) {
        const int g = t >> 2, qq = t & 3;
        const int ss = g / 10, o = g - ss * 10;
        float a = 0.f;
        const float* wr = Wo + o * 320;
        for (int k = qq; k < 320; k += 4) a = fmaf(flat[ss][k], wr[k], a);
        a += __shfl_xor(a, 1);
        a += __shfl_xor(a, 2);
        if (qq == 0 && b0 + ss < B) out[(size_t)(b0 + ss) * 10 + o] = a + bo[o];
    }
}

// ---------------------------------------------------------------------------
extern "C" void kernel_launch(void* const* d_in, const int* in_sizes, int n_in,
                              void* d_out, int out_size, void* d_ws, size_t ws_size,
                              hipStream_t stream)
{
    const float* x  = (const float*)d_in[0];
    const float* W1 = (const float*)d_in[1];
    const float* b1 = (const float*)d_in[2];
    const float* a1 = (const float*)d_in[3];
    const float* c1 = (const float*)d_in[4];
    const float* W2 = (const float*)d_in[5];
    const float* b2 = (const float*)d_in[6];
    const float* a2 = (const float*)d_in[7];
    const float* c2 = (const float*)d_in[8];
    const float* W3 = (const float*)d_in[9];
    const float* b3 = (const float*)d_in[10];
    const float* a3 = (const float*)d_in[11];
    const float* c3 = (const float*)d_in[12];
    const float* Wo = (const float*)d_in[13];
    const float* bo = (const float*)d_in[14];
    float* out = (float*)d_out;

    const int B = in_sizes[0] / 3072;   // 4096

    float* h1  = (float*)d_ws;                       // B*4096 f32
    float* h2  = h1 + (size_t)B * 4096;              // B*1280 f32
    float* Wp1 = h2 + (size_t)B * 1280;              // 1200
    float* Wp2 = Wp1 + 1200;                         // 8960
    float* Wp3 = Wp2 + 8960;                         // 11200
    double* dmeta = (double*)(Wp3 + 11200);          // 42 doubles (8B aligned)
    int* imeta = (int*)(dmeta + 42);                 // 56 ints
    int* qh2 = imeta + 56;                           // B ints
    int* qh3 = qh2 + B;

    prep_kernel<<<87, 256, 0, stream>>>(W1, a1, c1, W2, a2, c2, W3, a3, c3,
                                        dmeta, imeta, Wp1, Wp2, Wp3);
    conv1_kernel<<<(B + 3) / 4, 256, 0, stream>>>(x, Wp1, b1, imeta, dmeta, h1, qh2, B);
    conv2_kernel<<<(B + 3) / 4, 256, 0, stream>>>(h1, Wp2, b2, imeta + 16, qh2, dmeta, h2, qh3, B);
    conv3_kernel<<<(B + 3) / 4, 256, 0, stream>>>(h2, Wp3, b3, imeta + 36, qh3, Wo, bo, out, B);
}

// Round 12
// 461.696 us; speedup vs baseline: 9.1337x; 9.1337x over previous
//
#include <hip/hip_runtime.h>
#include <hip/hip_bf16.h>

#define EPSV 1e-12
#define RHASH 0.2

__device__ __forceinline__ int fmod2(double t) {
    // floor then mod 2 with numpy semantics (non-negative result)
    return (int)(((long long)floor(t)) & 1LL);
}

__device__ __forceinline__ void load_row6(const float* base, float* r) {
    float2 a0 = *(const float2*)(base);
    float2 a1 = *(const float2*)(base + 2);
    float2 a2 = *(const float2*)(base + 4);
    r[0] = a0.x; r[1] = a0.y; r[2] = a1.x; r[3] = a1.y; r[4] = a2.x; r[5] = a2.y;
}

__device__ __forceinline__ void load_row12(const float* base, float* r) {
    #pragma unroll
    for (int j = 0; j < 6; ++j) *(float2*)&r[2 * j] = *(const float2*)(base + 2 * j);
}

// 4 FMAs into acc[c][0..3] from rows cur/nxt
#define FMA4(c,kx,w) { float wg=(w); \
  acc[c][0]=fmaf(wg,cur[kx],acc[c][0]); acc[c][1]=fmaf(wg,cur[(kx)+1],acc[c][1]); \
  acc[c][2]=fmaf(wg,nxt[kx],acc[c][2]); acc[c][3]=fmaf(wg,nxt[(kx)+1],acc[c][3]); }

// ---------------------------------------------------------------------------
// layer_setup v2 (r9): wave-parallel reductions.
// dmeta layout: [0..2]=asum1, [3..18]=asum2, [19..38]=asum3, [39]=qc1,[40]=qc2,[41]=qc3
// imeta layout: [0..15]=kh1, [16..35]=kh2, [36..55]=kh3
// ---------------------------------------------------------------------------
__device__ void layer_setup(const float* W, const float* a, double cval,
                            int Co, int Ci, int* kh, double* asum, double* qc,
                            double* s_norm, float* Wbuf, float* abuf)
{
    const int t = threadIdx.x;
    const int w = t >> 6, ln = t & 63;
    const int D = Ci * 25;
    for (int i = t; i < Co * D; i += 256) Wbuf[i] = W[i];
    for (int i = t; i < D + 5; i += 256) abuf[i] = a[i];
    __syncthreads();
    // norms: wave-per-channel
    for (int co = w; co < Co; co += 4) {
        double s = 0;
        for (int j = ln; j < D; j += 64) { double x = (double)Wbuf[co * D + j]; s += x * x; }
        #pragma unroll
        for (int off = 32; off; off >>= 1) s += __shfl_xor(s, off);
        if (ln == 0) s_norm[co] = sqrt(s);
    }
    __syncthreads();
    if (t == 0) {
        double mx = 0;
        for (int i = 0; i < Co; ++i) mx = fmax(mx, s_norm[i]);
        s_norm[23] = 1.0 / (mx + EPSV);     // scratch slot: Co <= 20 < 23
    }
    __syncthreads();
    double scale = s_norm[23];
    // hash dot-products: wave-per-channel
    for (int co = w; co < Co; co += 4) {
        double dp = 0;
        for (int j = ln; j < D; j += 64) dp += (double)Wbuf[co * D + j] * (double)abuf[j];
        #pragma unroll
        for (int off = 32; off; off >>= 1) dp += __shfl_xor(dp, off);
        if (ln == 0) {
            dp *= scale;
            double n = s_norm[co] * scale;
            double p = n * n;               // n^2, n^4, n^8, n^16, n^32
            for (int m = 0; m < 5; ++m) { dp += p * (double)abuf[D + m]; p *= p; }
            kh[co] = fmod2((dp + cval) / RHASH);
        }
    }
    if (t >= 64 && t < 64 + Ci) {
        int c = t - 64;
        double s = 0;
        for (int j = 0; j < 25; ++j) s += (double)abuf[c * 25 + j];
        asum[c] = s;
    }
    if (t == 128) {
        double s = 0;
        for (int m = 0; m < 5; ++m) s += (double)abuf[D + m];
        *qc = 0.5 * s + cval;
    }
    __syncthreads();
}

// ---------------------------------------------------------------------------
// prep_kernel: fused setup + pack (r4). Blocks 0..2 = one hash layer each;
// blocks 3..86 = weight repack.
// Wp1: [ci3][ky5][kx5][co16] = 1200; Wp2: [ci16][ky5][cog4][28] = 8960;
// Wp3: [ci20][ky5][cog4][28] = 11200.
// ---------------------------------------------------------------------------
__global__ __launch_bounds__(256) void prep_kernel(
    const float* W1, const float* a1, const float* c1,
    const float* W2, const float* a2, const float* c2,
    const float* W3, const float* a3, const float* c3,
    double* dmeta, int* imeta,
    float* Wp1, float* Wp2, float* Wp3)
{
    __shared__ float Wbuf[10000];
    __shared__ float abuf[512];
    __shared__ double s_norm[24];
    const int blk = blockIdx.x;
    if (blk == 0) {
        layer_setup(W1, a1, (double)c1[0], 16, 3,  imeta + 0,  dmeta + 0,  dmeta + 39, s_norm, Wbuf, abuf);
    } else if (blk == 1) {
        layer_setup(W2, a2, (double)c2[0], 20, 16, imeta + 16, dmeta + 3,  dmeta + 40, s_norm, Wbuf, abuf);
    } else if (blk == 2) {
        layer_setup(W3, a3, (double)c3[0], 20, 20, imeta + 36, dmeta + 19, dmeta + 41, s_norm, Wbuf, abuf);
    } else {
        int i = (blk - 3) * 256 + threadIdx.x;
        if (i < 1200) {
            int co = i & 15, r = i >> 4;           // r = (ci*5+ky)*5+kx
            int kx = r % 5, r2 = r / 5, ky = r2 % 5, ci = r2 / 5;
            Wp1[i] = W1[co * 75 + ci * 25 + ky * 5 + kx];
        } else if (i < 1200 + 8960) {
            int k = i - 1200;
            int j = k % 28, r = k / 28;            // r = (ci*5+ky)*4+cog
            int cog = r % 4, r2 = r / 4, ky = r2 % 5, ci = r2 / 5;
            Wp2[k] = (j < 25) ? W2[(cog * 5 + j / 5) * 400 + ci * 25 + ky * 5 + (j % 5)] : 0.f;
        } else if (i < 1200 + 8960 + 11200) {
            int k = i - 10160;
            int j = k % 28, r = k / 28;
            int cog = r % 4, r2 = r / 4, ky = r2 % 5, ci = r2 / 5;
            Wp3[k] = (j < 25) ? W3[(cog * 5 + j / 5) * 500 + ci * 25 + ky * 5 + (j % 5)] : 0.f;
        }
    }
}

// ---------------------------------------------------------------------------
// conv1 v3 (r9-proven; r11's persistent v5 REVERTED: VGPR 256 + scratch
// spill -> 9.6GB HBM traffic, 3.9ms): x -> h1; block = 1 sample.
// thread = (cog4 x py16 x pxg4): 4 co x 2x8 strip; rolling rows; cog in
// lane bits 4-5 (broadcast). x stride 38 (2-way free). qh1 fused into
// staging (static channel index); fused qh2 epilogue.
// ---------------------------------------------------------------------------
__global__ __launch_bounds__(256) void conv1_kernel(
    const float* __restrict__ x, const float* __restrict__ Wp1,
    const float* __restrict__ b1, const int* __restrict__ kh1,
    const double* __restrict__ dmeta, float* __restrict__ h1,
    int* __restrict__ qh2)
{
    __shared__ float xs[3][36][38];
    __shared__ float Ws[1200];
    __shared__ double s_red[3][4];
    __shared__ double s_ch[16][4];

    const int b = blockIdx.x, t = threadIdx.x;
    const int w = t >> 6, ln = t & 63;

    for (int i = t; i < 3 * 36 * 38; i += 256) (&xs[0][0][0])[i] = 0.f;
    for (int i = t; i < 600; i += 256) ((float2*)Ws)[i] = ((const float2*)Wp1)[i];
    __syncthreads();   // zero-init visible before interior staging

    // staging with fused qh1 partial sums (c = j>>1 is compile-time static)
    const float2* xb2 = (const float2*)(x + (size_t)b * 3072);
    double psum[3] = {0, 0, 0};
    #pragma unroll
    for (int j = 0; j < 6; ++j) {
        int i = t + 256 * j;
        int rem = i & 511, row = rem >> 4, col2 = rem & 15;
        float2 v = xb2[i];
        *(float2*)&xs[j >> 1][row + 2][col2 * 2 + 2] = v;
        psum[j >> 1] += (double)v.x + (double)v.y;
    }
    #pragma unroll
    for (int c = 0; c < 3; ++c) {
        double s = psum[c];
        #pragma unroll
        for (int off = 32; off; off >>= 1) s += __shfl_xor(s, off);
        if (ln == 0) s_red[c][w] = s;
    }
    __syncthreads();   // covers xs staging AND s_red

    double dp = 0, nn = 0;
    #pragma unroll
    for (int c = 0; c < 3; ++c) {
        double cm = (s_red[c][0] + s_red[c][1] + s_red[c][2] + s_red[c][3]) * (1.0 / 1024.0);
        dp += cm * dmeta[c]; nn += cm * cm;
    }
    const int qh = fmod2((dp / (5.0 * sqrt(nn) + EPSV) + dmeta[39]) / RHASH);

    // thread decomposition: cog = lane bits 4-5; py spans 4 rows per wave
    const int cog = ln >> 4;
    const int py = 4 * w + ((ln >> 2) & 3), pxg = ln & 3;
    const int y0 = 2 * py, x0 = 8 * pxg;

    float accA[4][8], accB[4][8];
    #pragma unroll
    for (int c = 0; c < 4; ++c) {
        float bb = b1[cog * 4 + c];
        #pragma unroll
        for (int k = 0; k < 8; ++k) { accA[c][k] = bb; accB[c][k] = bb; }
    }

    #pragma unroll
    for (int ci = 0; ci < 3; ++ci) {
        float ra[12], rb[12];
        load_row12(&xs[ci][y0][x0],     ra);
        load_row12(&xs[ci][y0 + 1][x0], rb);
        #pragma unroll
        for (int ky = 0; ky < 5; ++ky) {
            const float4* wq = (const float4*)&Ws[((ci * 5 + ky) * 5) * 16 + cog * 4];
            #pragma unroll
            for (int kx = 0; kx < 5; ++kx) {
                float4 wv = wq[kx * 4];          // 4 co of this cog, stride 16 floats
                { float wg = wv.x;
                  #pragma unroll
                  for (int k = 0; k < 8; ++k) { accA[0][k] = fmaf(wg, ra[k + kx], accA[0][k]);
                                                accB[0][k] = fmaf(wg, rb[k + kx], accB[0][k]); } }
                { float wg = wv.y;
                  #pragma unroll
                  for (int k = 0; k < 8; ++k) { accA[1][k] = fmaf(wg, ra[k + kx], accA[1][k]);
                                                accB[1][k] = fmaf(wg, rb[k + kx], accB[1][k]); } }
                { float wg = wv.z;
                  #pragma unroll
                  for (int k = 0; k < 8; ++k) { accA[2][k] = fmaf(wg, ra[k + kx], accA[2][k]);
                                                accB[2][k] = fmaf(wg, rb[k + kx], accB[2][k]); } }
                { float wg = wv.w;
                  #pragma unroll
                  for (int k = 0; k < 8; ++k) { accA[3][k] = fmaf(wg, ra[k + kx], accA[3][k]);
                                                accB[3][k] = fmaf(wg, rb[k + kx], accB[3][k]); } }
            }
            if (ky < 4) {
                #pragma unroll
                for (int j = 0; j < 12; ++j) ra[j] = rb[j];
                load_row12(&xs[ci][y0 + ky + 2][x0], rb);
            }
        }
    }

    // masked pooled store (float4: 4 pooled px per co) + per-channel sums
    float* hb = h1 + (size_t)b * 4096 + py * 16 + pxg * 4;
    double csum[4];
    #pragma unroll
    for (int c = 0; c < 4; ++c) {
        int co = cog * 4 + c;
        float mask = (kh1[co] == qh) ? 1.f : 0.f;
        float v0 = fmaxf(fmaxf(accA[c][0], accA[c][1]), fmaxf(accB[c][0], accB[c][1]));
        float v1 = fmaxf(fmaxf(accA[c][2], accA[c][3]), fmaxf(accB[c][2], accB[c][3]));
        float v2 = fmaxf(fmaxf(accA[c][4], accA[c][5]), fmaxf(accB[c][4], accB[c][5]));
        float v3 = fmaxf(fmaxf(accA[c][6], accA[c][7]), fmaxf(accB[c][6], accB[c][7]));
        v0 = fmaxf(v0, 0.f) * mask; v1 = fmaxf(v1, 0.f) * mask;
        v2 = fmaxf(v2, 0.f) * mask; v3 = fmaxf(v3, 0.f) * mask;
        *(float4*)(hb + co * 256) = make_float4(v0, v1, v2, v3);
        csum[c] = (double)v0 + (double)v1 + (double)v2 + (double)v3;
    }
    // reduce over lane bits 0..3 (16 positions of this cog group)
    #pragma unroll
    for (int c = 0; c < 4; ++c) {
        double s = csum[c];
        s += __shfl_xor(s, 8); s += __shfl_xor(s, 4);
        s += __shfl_xor(s, 2); s += __shfl_xor(s, 1);
        if ((ln & 15) == 0) s_ch[cog * 4 + c][w] = s;
    }
    __syncthreads();
    if (t == 0) {
        double dp2 = 0, nn2 = 0;
        #pragma unroll
        for (int c = 0; c < 16; ++c) {
            double cm = (s_ch[c][0] + s_ch[c][1] + s_ch[c][2] + s_ch[c][3]) * (1.0 / 256.0);
            dp2 += cm * dmeta[3 + c]; nn2 += cm * cm;
        }
        qh2[b] = fmod2((dp2 / (5.0 * sqrt(nn2) + EPSV) + dmeta[40]) / RHASH);
    }
}

// ---------------------------------------------------------------------------
// conv2 v4 (r5/r9/r10-proven): h1 -> h2; block = 4 samples (wave=sample).
// thread = (s4 x cog4 x py8 x pxg2); 5co x 2x8 strip. T14 async-stage on x.
// VGPR 128 / LDS 37.9KB -> 4 blocks/CU. FROZEN — measured best (185us).
// ---------------------------------------------------------------------------
#define C2_XLOAD(CH, RX) { \
    _Pragma("unroll") \
    for (int j = 0; j < 8; ++j) { \
        int i = t + 256 * j, si = i >> 9, rem = i & 511, cil = rem >> 7, rr = rem & 127; \
        RX[j] = (b0 + si < B) ? ((const float2*)h1)[(size_t)(b0 + si) * 2048 + ((CH) * 4 + cil) * 128 + rr] \
                              : make_float2(0.f, 0.f); \
    } }

#define C2_XCOMMIT(RX) { \
    _Pragma("unroll") \
    for (int j = 0; j < 8; ++j) { \
        int i = t + 256 * j, si = i >> 9, rem = i & 511, cil = rem >> 7, rr = rem & 127; \
        int p2 = rr * 2, row = p2 >> 4, col = p2 & 15; \
        *(float2*)&xs[si][cil][row + 2][col + 2] = RX[j]; \
    } }

__global__ __launch_bounds__(256) void conv2_kernel(
    const float* __restrict__ h1, const float* __restrict__ Wp2,
    const float* __restrict__ b2, const int* __restrict__ kh2,
    const int* __restrict__ qh2, const double* __restrict__ dmeta,
    float* __restrict__ h2, int* __restrict__ qh3, int B)
{
    __shared__ float xs[4][4][20][22];   // [sample][ci][row][col] stride-22
    __shared__ float Ws[2240];           // [ci4][ky5][cog4][28]
    __shared__ double s_ch[4][20];

    const int b0 = blockIdx.x * 4, t = threadIdx.x;
    const int s = t >> 6, l = t & 63;
    const int cog = l >> 4, pos = l & 15;
    const int py = pos >> 1, pxg = pos & 1;
    const int b = b0 + s;

    for (int i = t; i < 4 * 4 * 20 * 22; i += 256) (&xs[0][0][0][0])[i] = 0.f;

    const int qh = (b < B) ? qh2[b] : 0;
    float accA[5][8], accB[5][8];
    #pragma unroll
    for (int c = 0; c < 5; ++c) {
        float bb = b2[cog * 5 + c];
        #pragma unroll
        for (int k = 0; k < 8; ++k) { accA[c][k] = bb; accB[c][k] = bb; }
    }

    float2 rx[8];
    C2_XLOAD(0, rx);
    __syncthreads();   // zero-init visible before chunk-0 commit

    for (int ch = 0; ch < 4; ++ch) {
        for (int i = t; i < 1120; i += 256)
            ((float2*)Ws)[i] = ((const float2*)(Wp2 + ch * 2240))[i];
        C2_XCOMMIT(rx);
        __syncthreads();
        if (ch < 3) C2_XLOAD(ch + 1, rx);   // issued post-barrier: hides under compute

        for (int cil = 0; cil < 4; ++cil) {
            float ra[12], rb[12];
            load_row12(&xs[s][cil][2 * py][8 * pxg],     ra);
            load_row12(&xs[s][cil][2 * py + 1][8 * pxg], rb);
            #pragma unroll
            for (int ky = 0; ky < 5; ++ky) {
                float wv[28];
                const float4* wp = (const float4*)&Ws[((cil * 5 + ky) * 4 + cog) * 28];
                *(float4*)&wv[0]  = wp[0];
                *(float4*)&wv[4]  = wp[1];
                *(float4*)&wv[8]  = wp[2];
                *(float4*)&wv[12] = wp[3];
                *(float4*)&wv[16] = wp[4];
                *(float4*)&wv[20] = wp[5];
                *(float4*)&wv[24] = wp[6];
                #pragma unroll
                for (int c = 0; c < 5; ++c) {
                    #pragma unroll
                    for (int kx = 0; kx < 5; ++kx) {
                        float wg = wv[c * 5 + kx];
                        #pragma unroll
                        for (int k = 0; k < 8; ++k) {
                            accA[c][k] = fmaf(wg, ra[k + kx], accA[c][k]);
                            accB[c][k] = fmaf(wg, rb[k + kx], accB[c][k]);
                        }
                    }
                }
                if (ky < 4) {
                    #pragma unroll
                    for (int j = 0; j < 12; ++j) ra[j] = rb[j];
                    load_row12(&xs[s][cil][2 * py + ky + 2][8 * pxg], rb);
                }
            }
        }
        __syncthreads();
    }

    // masked pooled store (float4: 4 pooled px per co) + fused qh3
    float* ob = h2 + (size_t)b * 1280 + py * 8 + pxg * 4;
    double csum[5];
    #pragma unroll
    for (int c = 0; c < 5; ++c) {
        int co = cog * 5 + c;
        float mask = (kh2[co] == qh) ? 1.f : 0.f;
        float v0 = fmaxf(fmaxf(accA[c][0], accA[c][1]), fmaxf(accB[c][0], accB[c][1]));
        float v1 = fmaxf(fmaxf(accA[c][2], accA[c][3]), fmaxf(accB[c][2], accB[c][3]));
        float v2 = fmaxf(fmaxf(accA[c][4], accA[c][5]), fmaxf(accB[c][4], accB[c][5]));
        float v3 = fmaxf(fmaxf(accA[c][6], accA[c][7]), fmaxf(accB[c][6], accB[c][7]));
        v0 = fmaxf(v0, 0.f) * mask; v1 = fmaxf(v1, 0.f) * mask;
        v2 = fmaxf(v2, 0.f) * mask; v3 = fmaxf(v3, 0.f) * mask;
        if (b < B) *(float4*)(ob + co * 64) = make_float4(v0, v1, v2, v3);
        csum[c] = (double)v0 + (double)v1 + (double)v2 + (double)v3;
    }
    #pragma unroll
    for (int c = 0; c < 5; ++c) {
        double sv = csum[c];
        sv += __shfl_xor(sv, 8); sv += __shfl_xor(sv, 4);
        sv += __shfl_xor(sv, 2); sv += __shfl_xor(sv, 1);
        if (pos == 0) s_ch[s][cog * 5 + c] = sv;
    }
    __syncthreads();
    if (l == 0 && b < B) {
        double dp2 = 0, nn2 = 0;
        #pragma unroll
        for (int c = 0; c < 20; ++c) {
            double cm = s_ch[s][c] * (1.0 / 64.0);
            dp2 += cm * dmeta[19 + c]; nn2 += cm * cm;
        }
        qh3[b] = fmod2((dp2 / (5.0 * sqrt(nn2) + EPSV) + dmeta[41]) / RHASH);
    }
}

// ---------------------------------------------------------------------------
// conv3 + linear v2 (r5/r9-proven): block = 4 samples, 256 threads;
// T14 async-stage split on Ws and x chunks.
// ---------------------------------------------------------------------------
#define C3_WLOAD(CH, RW) { \
    _Pragma("unroll") \
    for (int j = 0; j < 6; ++j) { \
        int i = t + 256 * j; \
        if (i < 1400) RW[j] = ((const float2*)(Wp3 + (CH) * 2800))[i]; \
    } }

#define C3_WCOMMIT(RW) { \
    _Pragma("unroll") \
    for (int j = 0; j < 6; ++j) { \
        int i = t + 256 * j; \
        if (i < 1400) ((float2*)Ws)[i] = RW[j]; \
    } }

#define C3_XLOAD(CH, RX) { \
    _Pragma("unroll") \
    for (int j = 0; j < 3; ++j) { \
        int i = t + 256 * j; \
        if (i < 640) { \
            int ss = i / 160, r = i - ss * 160, ci = r >> 5, rr = r & 31; \
            RX[j] = (b0 + ss < B) ? ((const float2*)(h2 + (size_t)(b0 + ss) * 1280 + ((CH) * 5 + ci) * 64))[rr] \
                                  : make_float2(0.f, 0.f); \
        } \
    } }

#define C3_XCOMMIT(RX) { \
    _Pragma("unroll") \
    for (int j = 0; j < 3; ++j) { \
        int i = t + 256 * j; \
        if (i < 640) { \
            int ss = i / 160, r = i - ss * 160, ci = r >> 5, rr = r & 31, p2 = rr * 2; \
            *(float2*)&xs[ss][ci][(p2 >> 3) + 2][(p2 & 7) + 2] = RX[j]; \
        } \
    } }

__global__ __launch_bounds__(256) void conv3_kernel(
    const float* __restrict__ h2, const float* __restrict__ Wp3,
    const float* __restrict__ b3, const int* __restrict__ kh3,
    const int* __restrict__ qh3,
    const float* __restrict__ Wo, const float* __restrict__ bo,
    float* __restrict__ out, int B)
{
    __shared__ float xs[4][5][12][12];
    __shared__ float Ws[2800];           // [ci5][ky5][cog4][28]
    __shared__ float flat[4][320];

    const int b0 = blockIdx.x * 4, t = threadIdx.x;
    const int s = t >> 6, q0 = t & 63, cog = q0 >> 4, pos = q0 & 15;
    const int py = pos >> 2, px = pos & 3;
    const int y0 = 2 * py, x0 = 2 * px;
    const int b = b0 + s;

    for (int i = t; i < 4 * 5 * 144; i += 256) (&xs[0][0][0][0])[i] = 0.f;

    const int qh = (b < B) ? qh3[b] : 0;
    float acc[5][4];
    #pragma unroll
    for (int c = 0; c < 5; ++c) {
        float bb = b3[cog * 5 + c];
        acc[c][0] = bb; acc[c][1] = bb; acc[c][2] = bb; acc[c][3] = bb;
    }

    float2 rw[6], rx[3];
    C3_WLOAD(0, rw);
    C3_XLOAD(0, rx);
    __syncthreads();   // zero-init visible before chunk-0 commit

    for (int ch = 0; ch < 4; ++ch) {
        C3_WCOMMIT(rw);
        C3_XCOMMIT(rx);
        __syncthreads();
        if (ch < 3) { C3_WLOAD(ch + 1, rw); C3_XLOAD(ch + 1, rx); }

        #pragma unroll
        for (int ci = 0; ci < 5; ++ci) {
            float cur[6], nxt[6];
            load_row6(&xs[s][ci][y0][x0], cur);
            load_row6(&xs[s][ci][y0 + 1][x0], nxt);
            #pragma unroll
            for (int ky = 0; ky < 5; ++ky) {
                const float* wrow = &Ws[((ci * 5 + ky) * 4 + cog) * 28];
                const float4* wq = (const float4*)wrow;
                float4 q;
                q = wq[0]; FMA4(0, 0, q.x) FMA4(0, 1, q.y) FMA4(0, 2, q.z) FMA4(0, 3, q.w)
                q = wq[1]; FMA4(0, 4, q.x) FMA4(1, 0, q.y) FMA4(1, 1, q.z) FMA4(1, 2, q.w)
                q = wq[2]; FMA4(1, 3, q.x) FMA4(1, 4, q.y) FMA4(2, 0, q.z) FMA4(2, 1, q.w)
                q = wq[3]; FMA4(2, 2, q.x) FMA4(2, 3, q.y) FMA4(2, 4, q.z) FMA4(3, 0, q.w)
                q = wq[4]; FMA4(3, 1, q.x) FMA4(3, 2, q.y) FMA4(3, 3, q.z) FMA4(3, 4, q.w)
                q = wq[5]; FMA4(4, 0, q.x) FMA4(4, 1, q.y) FMA4(4, 2, q.z) FMA4(4, 3, q.w)
                FMA4(4, 4, wrow[24])
                if (ky < 4) {
                    #pragma unroll
                    for (int j = 0; j < 6; ++j) cur[j] = nxt[j];
                    load_row6(&xs[s][ci][y0 + ky + 2][x0], nxt);
                }
            }
        }
        __syncthreads();
    }

    #pragma unroll
    for (int c = 0; c < 5; ++c) {
        int co = cog * 5 + c;
        float m = fmaxf(fmaxf(acc[c][0], acc[c][1]), fmaxf(acc[c][2], acc[c][3]));
        flat[s][co * 16 + pos] = fmaxf(m, 0.f) * ((kh3[co] == qh) ? 1.f : 0.f);
    }
    __syncthreads();

    // linear 320->10 for 4 samples: 40 (s,o) pairs x 4 lanes each
    if (t < 160) {
        const int g = t >> 2, qq = t & 3;
        const int ss = g / 10, o = g - ss * 10;
        float a = 0.f;
        const float* wr = Wo + o * 320;
        for (int k = qq; k < 320; k += 4) a = fmaf(flat[ss][k], wr[k], a);
        a += __shfl_xor(a, 1);
        a += __shfl_xor(a, 2);
        if (qq == 0 && b0 + ss < B) out[(size_t)(b0 + ss) * 10 + o] = a + bo[o];
    }
}

// ---------------------------------------------------------------------------
extern "C" void kernel_launch(void* const* d_in, const int* in_sizes, int n_in,
                              void* d_out, int out_size, void* d_ws, size_t ws_size,
                              hipStream_t stream)
{
    const float* x  = (const float*)d_in[0];
    const float* W1 = (const float*)d_in[1];
    const float* b1 = (const float*)d_in[2];
    const float* a1 = (const float*)d_in[3];
    const float* c1 = (const float*)d_in[4];
    const float* W2 = (const float*)d_in[5];
    const float* b2 = (const float*)d_in[6];
    const float* a2 = (const float*)d_in[7];
    const float* c2 = (const float*)d_in[8];
    const float* W3 = (const float*)d_in[9];
    const float* b3 = (const float*)d_in[10];
    const float* a3 = (const float*)d_in[11];
    const float* c3 = (const float*)d_in[12];
    const float* Wo = (const float*)d_in[13];
    const float* bo = (const float*)d_in[14];
    float* out = (float*)d_out;

    const int B = in_sizes[0] / 3072;   // 4096

    float* h1  = (float*)d_ws;                       // B*4096 f32
    float* h2  = h1 + (size_t)B * 4096;              // B*1280 f32
    float* Wp1 = h2 + (size_t)B * 1280;              // 1200
    float* Wp2 = Wp1 + 1200;                         // 8960
    float* Wp3 = Wp2 + 8960;                         // 11200
    double* dmeta = (double*)(Wp3 + 11200);          // 42 doubles (8B aligned)
    int* imeta = (int*)(dmeta + 42);                 // 56 ints
    int* qh2 = imeta + 56;                           // B ints
    int* qh3 = qh2 + B;

    prep_kernel<<<87, 256, 0, stream>>>(W1, a1, c1, W2, a2, c2, W3, a3, c3,
                                        dmeta, imeta, Wp1, Wp2, Wp3);
    conv1_kernel<<<B, 256, 0, stream>>>(x, Wp1, b1, imeta, dmeta, h1, qh2);
    conv2_kernel<<<(B + 3) / 4, 256, 0, stream>>>(h1, Wp2, b2, imeta + 16, qh2, dmeta, h2, qh3, B);
    conv3_kernel<<<(B + 3) / 4, 256, 0, stream>>>(h2, Wp3, b3, imeta + 36, qh3, Wo, bo, out, B);
}